// Round 2
// baseline (36.135 us; speedup 1.0000x reference)
//
#include <hip/hip_runtime.h>
#include <hip/hip_bf16.h>

// Problem constants (from reference): N=32, T=2048, C=512, V=500
#define RN 32
#define RT 2048
#define RC 512
#define RV 500

// float32(math.log(0.9))
#define LOG09 (-0.10536052f)

// Kernel 1: keep-flags via 64-lane ballot. One frame per thread, whole-chip parallel.
// grid = N*T/256 = 256 blocks, block = 256 threads (4 waves). 2048 % 64 == 0 so each
// wave's 64 frames are contiguous t's of a single row.
__global__ void fr_flags(const float* __restrict__ ctc,
                         const int* __restrict__ x_lens,
                         const int* __restrict__ blank_id_p,
                         unsigned long long* __restrict__ flag_words) // [N*T/64]
{
    const int g = blockIdx.x * 256 + threadIdx.x;   // global frame id
    const int n = g >> 11;                           // / T
    const int t = g & (RT - 1);                      // % T
    const int blank = blank_id_p[0];

    const bool keep = (t < x_lens[n]) &&
                      (ctc[(size_t)g * RV + blank] < LOG09);
    const unsigned long long b = __ballot(keep);
    if ((threadIdx.x & 63) == 0) {
        flag_words[g >> 6] = b;
    }
}

// Kernel 2: per-row scan of 32 flag words -> src_idx map + lengths.
// grid = N blocks, block = 64 threads (1 wave); lanes 0..31 active, lane w owns word w.
__global__ void fr_scan(const unsigned long long* __restrict__ flag_words,
                        int* __restrict__ src_idx,   // [N*T] in ws
                        int* __restrict__ lens_i,    // [N]   in ws
                        float* __restrict__ lens_f)  // [N]   tail of d_out
{
    const int n    = blockIdx.x;
    const int lane = threadIdx.x;    // 0..63

    unsigned long long word = 0;
    int cnt = 0;
    if (lane < 32) {
        word = flag_words[n * 32 + lane];
        cnt  = __popcll(word);
    }

    // Inclusive scan over lanes 0..31 (lanes >=32 carry zeros, harmless).
    int incl = cnt;
#pragma unroll
    for (int off = 1; off < 32; off <<= 1) {
        int v = __shfl_up(incl, off, 64);
        if (lane >= off) incl += v;
    }
    const int total = __shfl(incl, 31, 64);

    if (lane < 32) {
        int pos = incl - cnt;                 // exclusive prefix
        int* srow = src_idx + n * RT;
        const int base = lane * 64;
        unsigned long long w = word;
        while (w) {
            const int j = __ffsll((long long)w) - 1;
            srow[pos++] = base + j;
            w &= w - 1;
        }
    }
    if (lane == 0) {
        lens_i[n] = total;
        lens_f[n] = (float)total;   // harness reads concatenated output as f32
    }
}

// Kernel 3: gather/zero-fill every output row.
// Each block (256 thr) writes 2 output rows; each row = 512 floats = 128 float4.
__global__ void fr_gather(const float* __restrict__ x,
                          const int* __restrict__ src_idx,
                          const int* __restrict__ lens_i,
                          float4* __restrict__ out)
{
    const int r    = blockIdx.x * 2 + (threadIdx.x >> 7);  // output row in [0, N*T)
    const int lane = threadIdx.x & 127;
    const int n = r >> 11;        // / T
    const int p = r & (RT - 1);   // % T

    float4 v = make_float4(0.f, 0.f, 0.f, 0.f);
    if (p < lens_i[n]) {
        const int t = src_idx[n * RT + p];
        const float4* xr = (const float4*)(x + ((size_t)n * RT + t) * RC);
        v = xr[lane];
    }
    out[(size_t)r * (RC / 4) + lane] = v;
}

extern "C" void kernel_launch(void* const* d_in, const int* in_sizes, int n_in,
                              void* d_out, int out_size, void* d_ws, size_t ws_size,
                              hipStream_t stream) {
    const float* x        = (const float*)d_in[0];   // [N, T, C] f32
    const int*   x_lens   = (const int*)d_in[1];     // [N] int32
    const float* ctc      = (const float*)d_in[2];   // [N, T, V] f32
    const int*   blank_id = (const int*)d_in[3];     // scalar

    float* out    = (float*)d_out;                   // [N*T*C] + [N] lens (as f32)
    float* lens_f = out + (size_t)RN * RT * RC;

    int* src_idx = (int*)d_ws;                                   // [N*T]
    int* lens_i  = src_idx + RN * RT;                            // [N]
    unsigned long long* flag_words =
        (unsigned long long*)(lens_i + RN + (RN & 1));           // [N*T/64], 8B-aligned

    fr_flags<<<(RN * RT) / 256, 256, 0, stream>>>(ctc, x_lens, blank_id, flag_words);
    fr_scan<<<RN, 64, 0, stream>>>(flag_words, src_idx, lens_i, lens_f);
    fr_gather<<<(RN * RT) / 2, 256, 0, stream>>>(x, src_idx, lens_i, (float4*)out);
}

// Round 3
// 35.413 us; speedup vs baseline: 1.0204x; 1.0204x over previous
//
#include <hip/hip_runtime.h>
#include <hip/hip_bf16.h>

// Problem constants (from reference): N=32, T=2048, C=512, V=500
#define RN 32
#define RT 2048
#define RC 512
#define RV 500

// float32(math.log(0.9))
#define LOG09 (-0.10536052f)

typedef unsigned long long ull;

// Kernel 1: keep-flags via 64-lane ballot. One frame per thread, whole-chip parallel.
// grid = N*T/256 = 256 blocks. Each wave's 64 frames are contiguous t's of one row.
__global__ void fr_flags(const float* __restrict__ ctc,
                         const int* __restrict__ x_lens,
                         const int* __restrict__ blank_id_p,
                         ull* __restrict__ flag_words) // [N*T/64] = [1024]
{
    const int g = blockIdx.x * 256 + threadIdx.x;   // global frame id
    const int n = g >> 11;                           // / T
    const int t = g & (RT - 1);                      // % T
    const int blank = blank_id_p[0];

    const bool keep = (t < x_lens[n]) &&
                      (ctc[(size_t)g * RV + blank] < LOG09);
    const ull b = __ballot(keep);
    if ((threadIdx.x & 63) == 0) {
        flag_words[g >> 6] = b;
    }
}

// Kernel 2: fused scan + gather. 32 output rows per block (uniform n).
// grid = N*T/32 = 2048 blocks x 256 threads. Wave 0 resolves the 32 source
// frame indices from the row's flag words; then all threads stream float4.
__global__ void fr_gather(const float* __restrict__ x,
                          const ull* __restrict__ flag_words,
                          float* __restrict__ out,
                          float* __restrict__ lens_f)
{
    const int blk    = blockIdx.x;
    const int n      = blk >> 6;            // 64 blocks per row
    const int base_p = (blk & 63) * 32;
    const int tid    = threadIdx.x;

    __shared__ ull sh_w[32];
    __shared__ int sh_incl[32];
    __shared__ int sh_t[32];
    __shared__ int sh_total;

    if (tid < 64) {
        ull w = 0; int c = 0;
        if (tid < 32) { w = flag_words[n * 32 + tid]; c = __popcll(w); }
        int incl = c;
#pragma unroll
        for (int off = 1; off < 32; off <<= 1) {
            int v = __shfl_up(incl, off, 64);
            if (tid >= off) incl += v;
        }
        if (tid < 32) { sh_w[tid] = w; sh_incl[tid] = incl; }
        if (tid == 31) sh_total = incl;
    }
    __syncthreads();

    const int total = sh_total;
    if (tid < 32) {
        const int p = base_p + tid;
        int t = -1;
        if (p < total) {
            // smallest wi with sh_incl[wi] > p  (incl is non-decreasing)
            int wi = 0;
#pragma unroll
            for (int step = 16; step; step >>= 1) {
                const int probe = wi + step - 1;
                if (probe < 32 && sh_incl[probe] <= p) wi += step;
            }
            const int excl = (wi > 0) ? sh_incl[wi - 1] : 0;
            int r = p - excl;
            // select r-th set bit of sh_w[wi]
            const ull w = sh_w[wi];
            int pos = 0;
#pragma unroll
            for (int b = 32; b; b >>= 1) {
                const ull m = ((1ull << b) - 1) << pos;
                const int c2 = __popcll(w & m);
                if (r >= c2) { r -= c2; pos += b; }
            }
            t = wi * 64 + pos;
        }
        sh_t[tid] = t;
    }
    if (base_p == 0 && tid == 31) {
        // tid 31 is in wave 0; sh_total already set by this lane
        lens_f[n] = (float)sh_total;
    }
    __syncthreads();

    const float4* xbase = (const float4*)x + (size_t)n * RT * (RC / 4);
    float4* outr = (float4*)out + ((size_t)(n * RT + base_p)) * (RC / 4);
#pragma unroll
    for (int i = 0; i < 16; ++i) {
        const int idx  = i * 256 + tid;
        const int rl   = idx >> 7;        // local row 0..31
        const int lane = idx & 127;
        const int t = sh_t[rl];
        float4 v = make_float4(0.f, 0.f, 0.f, 0.f);
        if (t >= 0) v = xbase[(size_t)t * (RC / 4) + lane];
        outr[(size_t)rl * (RC / 4) + lane] = v;
    }
}

extern "C" void kernel_launch(void* const* d_in, const int* in_sizes, int n_in,
                              void* d_out, int out_size, void* d_ws, size_t ws_size,
                              hipStream_t stream) {
    const float* x        = (const float*)d_in[0];   // [N, T, C] f32
    const int*   x_lens   = (const int*)d_in[1];     // [N] int32
    const float* ctc      = (const float*)d_in[2];   // [N, T, V] f32
    const int*   blank_id = (const int*)d_in[3];     // scalar

    float* out    = (float*)d_out;                   // [N*T*C] + [N] lens (as f32)
    float* lens_f = out + (size_t)RN * RT * RC;

    ull* flag_words = (ull*)d_ws;                    // [N*T/64] = 8 KB

    fr_flags<<<(RN * RT) / 256, 256, 0, stream>>>(ctc, x_lens, blank_id, flag_words);
    fr_gather<<<(RN * RT) / 32, 256, 0, stream>>>(x, flag_words, out, lens_f);
}